// Round 13
// baseline (210.739 us; speedup 1.0000x reference)
//
#include <hip/hip_runtime.h>
#include <hip/hip_bf16.h>

// Sizes (fixed by the problem, N/E/G derived from in_sizes at launch)
#define FH 96      // F == H == 96
#define GU 32      // U
#define GA 16      // A
#define NG 64      // G

typedef __attribute__((ext_vector_type(8))) short bf16x8;
typedef __attribute__((ext_vector_type(8))) unsigned short u16x8;
typedef __attribute__((ext_vector_type(4))) float f32x4;

// fp32 -> bf16 (RNE) and back, as raw bit ops
static __device__ __forceinline__ unsigned short f2bf(float f) {
    unsigned int u = __float_as_uint(f);
    unsigned int r = (u + 0x7fffu + ((u >> 16) & 1u)) >> 16;
    return (unsigned short)r;
}
static __device__ __forceinline__ float bf2f(unsigned short h) {
    return __uint_as_float(((unsigned int)h) << 16);
}

// ---------------------------------------------------------------------------
// init_k: zero the atomic regions (blocks [0, nZero)) + convW pre-swizzle
// (blocks nZero, nZero+1). Independent work fused to save a launch.
__global__ __launch_bounds__(256) void init_k(float4* __restrict__ zp, int n4,
                                              int nZeroBlocks,
                                              const float* __restrict__ W1,
                                              const float* __restrict__ W2,
                                              unsigned short* __restrict__ WB1,
                                              unsigned short* __restrict__ WB2) {
    int b = blockIdx.x;
    if (b < nZeroBlocks) {
        int i = b * blockDim.x + threadIdx.x;
        if (i < n4) zp[i] = make_float4(0.f, 0.f, 0.f, 0.f);
    } else {
        int half = b - nZeroBlocks;          // 0 or 1
        const float* W = half ? W2 : W1;
        unsigned short* WB = half ? WB2 : WB1;
        for (int idx = threadIdx.x; idx < 2 * 3 * 6 * 64 * 8; idx += 256) {
            int j = idx & 7;
            int lane = (idx >> 3) & 63;
            int frag = idx >> 9;            // 0..35
            int cg = frag % 6;
            int rest = frag / 6;            // t*3 + ks
            int ks = rest % 3;
            int t = rest / 3;
            int k = ks * 32 + (lane >> 4) * 8 + j;
            int n = cg * 16 + (lane & 15);
            float w = W[k * FH + n];
            unsigned short h = f2bf(w);
            WB[idx] = (t == 0) ? h : f2bf(w - bf2f(h));
        }
    }
}

// Kernel 1: in-degree count + per-edge rank (int atomics, exact)
__global__ void count_deg_k(const int* __restrict__ dst, int* __restrict__ deg,
                            unsigned short* __restrict__ rank16, int E) {
    int e = blockIdx.x * blockDim.x + threadIdx.x;
    if (e < E) rank16[e] = (unsigned short)atomicAdd(&deg[dst[e]], 1);
}

// emit_k (self-based): each block computes its own global prefix by summing
// deg[0..base) directly (L2-resident, <=49k ints), then per-chunk exclusive
// scan + writes rowstart + fused dis = rsqrt(deg+1). Replaces partial+emit.
__global__ __launch_bounds__(256) void emit_k(const int* __restrict__ deg,
                                              int* __restrict__ rowstart,
                                              float* __restrict__ dis, int n) {
    __shared__ int sh[256];
    int t = threadIdx.x;
    int base = blockIdx.x * 1024;

    // phase A: blockBase = sum(deg[0..base))
    int pre = 0;
    for (int i = t; i < base; i += 256) pre += deg[i];
    sh[t] = pre;
    __syncthreads();
    for (int off = 128; off > 0; off >>= 1) {
        if (t < off) sh[t] += sh[t + off];
        __syncthreads();
    }
    int blockBase = sh[0];
    __syncthreads();

    // phase B: per-chunk exclusive scan over this block's 1024 degs
    int d[4];
    int s = 0;
#pragma unroll
    for (int j = 0; j < 4; j++) {
        int i = base + t * 4 + j;
        d[j] = (i < n) ? deg[i] : 0;
        s += d[j];
    }
    sh[t] = s;
    __syncthreads();
    for (int off = 1; off < 256; off <<= 1) {
        int v = 0;
        if (t >= off) v = sh[t - off];
        __syncthreads();
        if (t >= off) sh[t] += v;
        __syncthreads();
    }
    int run = blockBase + ((t == 0) ? 0 : sh[t - 1]);
#pragma unroll
    for (int j = 0; j < 4; j++) {
        int i = base + t * 4 + j;
        if (i < n) {
            rowstart[i] = run;
            dis[i] = rsqrtf((float)d[j] + 1.0f);
        }
        run += d[j];
    }
    if (blockIdx.x == gridDim.x - 1 && t == 255) rowstart[n] = run;
}

// Kernel 4: fill CSR — atomic-free (rank precomputed), uint16 entries,
// non-temporal scattered stores (skip L2 allocation on write churn).
__global__ void fill_k(const int* __restrict__ src, const int* __restrict__ dst,
                       const int* __restrict__ rowstart,
                       const unsigned short* __restrict__ rank16,
                       unsigned short* __restrict__ csr, int E) {
    int e = blockIdx.x * blockDim.x + threadIdx.x;
    if (e < E) {
        int pos = rowstart[dst[e]] + (int)rank16[e];
        __builtin_nontemporal_store((unsigned short)src[e], &csr[pos]);
    }
}

// ---------------------------------------------------------------------------
// MFMA GEMM: Yb[r][c] = bf16( (sum_k X[r][k]*W[k][c]) * scale[r] ).
// INMODE 0: A from fp32 Xf, split hi/lo in-register, 3 terms (AhBh+AhBl+AlBh).
// INMODE 1: A from bf16 Xb, 2 terms (AhBh+AhBl).
// Block: 64 rows x 96 cols, 4 waves as 2 wave-rows x 2 wave-cols. No LDS.
template <int INMODE>
__global__ __launch_bounds__(256, 3) void gemm_mfma_k(
    const float* __restrict__ Xf, const unsigned short* __restrict__ Xb,
    const unsigned short* __restrict__ WB, const float* __restrict__ scale,
    unsigned short* __restrict__ Yb, int nrows) {
    int lane = threadIdx.x & 63;
    int wid  = threadIdx.x >> 6;
    int wr = wid >> 1, wc = wid & 1;
    int row0 = blockIdx.x * 64 + wr * 32;

    // B fragments in registers for the whole kernel (18 x b128)
    bf16x8 b[2][3][3];
#pragma unroll
    for (int t = 0; t < 2; t++)
#pragma unroll
        for (int ks = 0; ks < 3; ks++)
#pragma unroll
            for (int cg = 0; cg < 3; cg++) {
                int frag = (t * 3 + ks) * 6 + wc * 3 + cg;
                b[t][ks][cg] = *(const bf16x8*)(WB + frag * 512 + lane * 8);
            }

    f32x4 acc[2][3];
#pragma unroll
    for (int rg = 0; rg < 2; rg++)
#pragma unroll
        for (int cg = 0; cg < 3; cg++) acc[rg][cg] = (f32x4){0.f, 0.f, 0.f, 0.f};

    int r0 = lane & 15;
    int kcol = (lane >> 4) * 8;
#pragma unroll
    for (int ks = 0; ks < 3; ks++) {
        bf16x8 ah[2], al[2];
#pragma unroll
        for (int rg = 0; rg < 2; rg++) {
            if (INMODE == 1) {
                size_t off = (size_t)(row0 + rg * 16 + r0) * FH + ks * 32 + kcol;
                ah[rg] = *(const bf16x8*)(Xb + off);
            } else {
                int rr = row0 + rg * 16 + r0;
                if (rr >= nrows) rr = nrows - 1;
                const float* xp = Xf + (size_t)rr * FH + ks * 32 + kcol;
                float4 v0 = *(const float4*)xp;
                float4 v1 = *(const float4*)(xp + 4);
                float xv[8] = {v0.x, v0.y, v0.z, v0.w, v1.x, v1.y, v1.z, v1.w};
                bf16x8 hh, ll;
#pragma unroll
                for (int j = 0; j < 8; j++) {
                    unsigned short h = f2bf(xv[j]);
                    hh[j] = (short)h;
                    ll[j] = (short)f2bf(xv[j] - bf2f(h));
                }
                ah[rg] = hh;
                al[rg] = ll;
            }
        }
#pragma unroll
        for (int rg = 0; rg < 2; rg++)
#pragma unroll
            for (int cg = 0; cg < 3; cg++)
                acc[rg][cg] = __builtin_amdgcn_mfma_f32_16x16x32_bf16(
                    ah[rg], b[0][ks][cg], acc[rg][cg], 0, 0, 0);
#pragma unroll
        for (int rg = 0; rg < 2; rg++)
#pragma unroll
            for (int cg = 0; cg < 3; cg++)
                acc[rg][cg] = __builtin_amdgcn_mfma_f32_16x16x32_bf16(
                    ah[rg], b[1][ks][cg], acc[rg][cg], 0, 0, 0);
        if (INMODE == 0) {
#pragma unroll
            for (int rg = 0; rg < 2; rg++)
#pragma unroll
                for (int cg = 0; cg < 3; cg++)
                    acc[rg][cg] = __builtin_amdgcn_mfma_f32_16x16x32_bf16(
                        al[rg], b[0][ks][cg], acc[rg][cg], 0, 0, 0);
        }
    }

    // Epilogue: C/D layout col=lane&15, row=(lane>>4)*4+reg (m89-verified)
#pragma unroll
    for (int rg = 0; rg < 2; rg++) {
#pragma unroll
        for (int r = 0; r < 4; r++) {
            int row = row0 + rg * 16 + (lane >> 4) * 4 + r;
            if (row < nrows) {
                float s = scale[row];
#pragma unroll
                for (int cg = 0; cg < 3; cg++) {
                    int col = wc * 48 + cg * 16 + (lane & 15);
                    Yb[(size_t)row * FH + col] = f2bf(acc[rg][cg][r] * s);
                }
            }
        }
    }
}

// ---------------------------------------------------------------------------
// Gather: 12 threads/node, ushort8 (16B) loads, strip-8 (8 outstanding loads),
// fp32 accumulate, bf16 output. Used for both layers.
__global__ __launch_bounds__(256) void gather12_k(
    const unsigned short* __restrict__ hXb, const float* __restrict__ dis,
    const int* __restrict__ rowstart, const unsigned short* __restrict__ csr,
    const float* __restrict__ bias, unsigned short* __restrict__ outB, int n) {
    int idx = blockIdx.x * blockDim.x + threadIdx.x;
    if (idx >= n * 12) return;
    int node = idx / 12;
    int f8 = (idx - node * 12) * 8;
    int s = rowstart[node];
    int e = rowstart[node + 1];
    u16x8 sv = *(const u16x8*)&hXb[node * FH + f8];
    float a[8];
#pragma unroll
    for (int j = 0; j < 8; j++) a[j] = bf2f((unsigned short)sv[j]);
    int p = s;
    for (; p + 8 <= e; p += 8) {
        int i0 = csr[p],     i1 = csr[p + 1], i2 = csr[p + 2], i3 = csr[p + 3];
        int i4 = csr[p + 4], i5 = csr[p + 5], i6 = csr[p + 6], i7 = csr[p + 7];
        u16x8 v0 = *(const u16x8*)&hXb[i0 * FH + f8];
        u16x8 v1 = *(const u16x8*)&hXb[i1 * FH + f8];
        u16x8 v2 = *(const u16x8*)&hXb[i2 * FH + f8];
        u16x8 v3 = *(const u16x8*)&hXb[i3 * FH + f8];
        u16x8 v4 = *(const u16x8*)&hXb[i4 * FH + f8];
        u16x8 v5 = *(const u16x8*)&hXb[i5 * FH + f8];
        u16x8 v6 = *(const u16x8*)&hXb[i6 * FH + f8];
        u16x8 v7 = *(const u16x8*)&hXb[i7 * FH + f8];
#pragma unroll
        for (int j = 0; j < 8; j++) {
            a[j] += ((bf2f((unsigned short)v0[j]) + bf2f((unsigned short)v1[j]))
                   + (bf2f((unsigned short)v2[j]) + bf2f((unsigned short)v3[j])))
                  + ((bf2f((unsigned short)v4[j]) + bf2f((unsigned short)v5[j]))
                   + (bf2f((unsigned short)v6[j]) + bf2f((unsigned short)v7[j])));
        }
    }
    for (; p + 4 <= e; p += 4) {
        int i0 = csr[p], i1 = csr[p + 1], i2 = csr[p + 2], i3 = csr[p + 3];
        u16x8 v0 = *(const u16x8*)&hXb[i0 * FH + f8];
        u16x8 v1 = *(const u16x8*)&hXb[i1 * FH + f8];
        u16x8 v2 = *(const u16x8*)&hXb[i2 * FH + f8];
        u16x8 v3 = *(const u16x8*)&hXb[i3 * FH + f8];
#pragma unroll
        for (int j = 0; j < 8; j++) {
            a[j] += (bf2f((unsigned short)v0[j]) + bf2f((unsigned short)v1[j]))
                  + (bf2f((unsigned short)v2[j]) + bf2f((unsigned short)v3[j]));
        }
    }
    for (; p < e; p++) {
        int i0 = csr[p];
        u16x8 v0 = *(const u16x8*)&hXb[i0 * FH + f8];
#pragma unroll
        for (int j = 0; j < 8; j++) a[j] += bf2f((unsigned short)v0[j]);
    }
    float dn = dis[node];
    float4 bv0 = *(const float4*)&bias[f8];
    float4 bv1 = *(const float4*)&bias[f8 + 4];
    float bb[8] = {bv0.x, bv0.y, bv0.z, bv0.w, bv1.x, bv1.y, bv1.z, bv1.w};
    u16x8 hh;
#pragma unroll
    for (int j = 0; j < 8; j++) hh[j] = f2bf(fmaxf(a[j] * dn + bb[j], 0.0f));
    *(u16x8*)&outB[node * FH + f8] = hh;
}

// Kernel 7: pooling — batch is SORTED; register accumulation with boundary
// flush. CH=32 nodes/block -> ~1564 blocks for latency hiding.
__global__ __launch_bounds__(128) void pool3_k(const unsigned short* __restrict__ h,
                                               const int* __restrict__ bat,
                                               float* __restrict__ pooled,
                                               float* __restrict__ cnt, int n) {
    const int CH = 32;
    int beg = blockIdx.x * CH;
    if (beg >= n) return;
    int end = min(beg + CH, n);
    int t = threadIdx.x;
    if (t < FH) {
        float acc = 0.f;
        int g = bat[beg];
        for (int node = beg; node < end; ++node) {
            int gg = bat[node];
            if (gg != g) { atomicAdd(&pooled[g * FH + t], acc); acc = 0.f; g = gg; }
            acc += bf2f(h[(size_t)node * FH + t]);
        }
        atomicAdd(&pooled[g * FH + t], acc);
    } else if (t == FH) {
        float c = 0.f;
        int g = bat[beg];
        for (int node = beg; node < end; ++node) {
            int gg = bat[node];
            if (gg != g) { atomicAdd(&cnt[g], c); c = 0.f; g = gg; }
            c += 1.f;
        }
        atomicAdd(&cnt[g], c);
    }
}

// Kernel 8: heads — one block per graph
__global__ __launch_bounds__(128) void head_k(const float* __restrict__ pooled,
                                              const float* __restrict__ cnt,
                                              const float* __restrict__ u,
                                              const float* __restrict__ aW1, const float* __restrict__ ab1,
                                              const float* __restrict__ aW2, const float* __restrict__ ab2,
                                              const float* __restrict__ cW1, const float* __restrict__ cb1,
                                              const float* __restrict__ cW2, const float* __restrict__ cb2,
                                              float* __restrict__ out, int G) {
    int g = blockIdx.x;
    int t = threadIdx.x;
    __shared__ float comb[FH + GU];
    __shared__ float hidA[FH];
    __shared__ float hidC[FH];
    __shared__ float tmp[FH];
    float c = fmaxf(cnt[g], 1.0f);
    if (t < FH) comb[t] = pooled[g * FH + t] / c;
    else if (t < FH + GU) comb[t] = u[g * GU + (t - FH)];
    __syncthreads();
    if (t < FH) {
        float a = ab1[t], cc = cb1[t];
        for (int k = 0; k < FH + GU; k++) {
            float cv = comb[k];
            a += cv * aW1[k * FH + t];
            cc += cv * cW1[k * FH + t];
        }
        hidA[t] = fmaxf(a, 0.0f);
        hidC[t] = fmaxf(cc, 0.0f);
    }
    __syncthreads();
    if (t < GA) {
        float a = ab2[t];
        for (int j = 0; j < FH; j++) a += hidA[j] * aW2[j * GA + t];
        out[g * GA + t] = a;
    }
    if (t >= 32 && t < 32 + FH) tmp[t - 32] = hidC[t - 32] * cW2[t - 32];
    __syncthreads();
    if (t == 0) {
        float v = cb2[0];
        for (int j = 0; j < FH; j++) v += tmp[j];
        out[G * GA + g] = v;
    }
}

extern "C" void kernel_launch(void* const* d_in, const int* in_sizes, int n_in,
                              void* d_out, int out_size, void* d_ws, size_t ws_size,
                              hipStream_t stream) {
    const float* x   = (const float*)d_in[0];
    const int*   ei  = (const int*)d_in[1];
    const int*   bat = (const int*)d_in[2];
    const float* u   = (const float*)d_in[3];
    const float* W1  = (const float*)d_in[4];
    const float* b1  = (const float*)d_in[5];
    const float* W2  = (const float*)d_in[6];
    const float* b2  = (const float*)d_in[7];
    const float* aW1 = (const float*)d_in[8];
    const float* ab1 = (const float*)d_in[9];
    const float* aW2 = (const float*)d_in[10];
    const float* ab2 = (const float*)d_in[11];
    const float* cW1 = (const float*)d_in[12];
    const float* cb1 = (const float*)d_in[13];
    const float* cW2 = (const float*)d_in[14];
    const float* cb2 = (const float*)d_in[15];
    float* out = (float*)d_out;

    const int N = in_sizes[0] / FH;
    const int E = in_sizes[1] / 2;
    const int G = in_sizes[3] / GU;
    const int NPAD = (N + 63) / 64 * 64;   // 50048

    const int* src = ei;
    const int* dst = ei + E;

    // Workspace layout (float units, 64-aligned blocks)
    float* ws = (float*)d_ws;
    size_t o = 0;
    int*   degI     = (int*)(ws + o);   o += NPAD;
    float* pooled   = ws + o;           o += NG * FH;
    float* cnt      = ws + o;           o += 64;
    size_t zero_elems = o;                                     // zero [0, o)
    float* dis      = ws + o;           o += NPAD;
    int*   rowstart = (int*)(ws + o);   o += NPAD;             // N+1
    unsigned short* rank16 = (unsigned short*)(ws + o); o += ((size_t)(E + 1) / 2 + 63) / 64 * 64;
    unsigned short* csr16  = (unsigned short*)(ws + o); o += ((size_t)(E + 1) / 2 + 63) / 64 * 64;
    unsigned short* WB1 = (unsigned short*)(ws + o); o += 9216;  // 18432 ushorts
    unsigned short* WB2 = (unsigned short*)(ws + o); o += 9216;
    unsigned short* XhB = (unsigned short*)(ws + o); o += (size_t)NPAD * FH / 2;  // layer1 out / layer2 out
    unsigned short* hXb = (unsigned short*)(ws + o); o += (size_t)NPAD * FH / 2;  // GEMM out
    (void)ws_size;

    unsigned short* h2b = XhB;   // layer-2 gather output (XhB dead after gemm2)

    int gridE = (E + 255) / 256;
    int gridG12 = (N * 12 + 255) / 256;
    int gridMfma = NPAD / 64;
    int nbScan = (N + 1023) / 1024;
    int gridPool = (N + 31) / 32;
    int n4zero = (int)(zero_elems / 4);
    int gridZero = (n4zero + 255) / 256;

    // init: zero atomic regions + convW (fused, independent work)
    init_k<<<gridZero + 2, 256, 0, stream>>>((float4*)ws, n4zero, gridZero,
                                             W1, W2, WB1, WB2);

    count_deg_k<<<gridE, 256, 0, stream>>>(dst, degI, rank16, E);
    emit_k<<<nbScan, 256, 0, stream>>>(degI, rowstart, dis, N);
    fill_k<<<gridE, 256, 0, stream>>>(src, dst, rowstart, rank16, csr16, E);

    // Layer 1 (GEMM reads fp32 x directly, converts+splits in-register)
    gemm_mfma_k<0><<<gridMfma, 256, 0, stream>>>(x, (const unsigned short*)nullptr,
                                                 WB1, dis, hXb, N);
    gather12_k<<<gridG12, 256, 0, stream>>>(hXb, dis, rowstart, csr16, b1, XhB, N);
    // Layer 2 (A = bf16, 2-term)
    gemm_mfma_k<1><<<gridMfma, 256, 0, stream>>>((const float*)nullptr, XhB,
                                                 WB2, dis, hXb, N);
    gather12_k<<<gridG12, 256, 0, stream>>>(hXb, dis, rowstart, csr16, b2, h2b, N);

    // Pool (sorted-batch register accumulation, CH=32) + heads
    pool3_k<<<gridPool, 128, 0, stream>>>(h2b, bat, pooled, cnt, N);
    head_k<<<G, 128, 0, stream>>>(pooled, cnt, u, aW1, ab1, aW2, ab2,
                                  cW1, cb1, cW2, cb2, out, G);
}

// Round 14
// 175.288 us; speedup vs baseline: 1.2022x; 1.2022x over previous
//
#include <hip/hip_runtime.h>
#include <hip/hip_bf16.h>

// Sizes (fixed by the problem, N/E/G derived from in_sizes at launch)
#define FH 96      // F == H == 96
#define GU 32      // U
#define GA 16      // A
#define NG 64      // G

typedef __attribute__((ext_vector_type(8))) short bf16x8;
typedef __attribute__((ext_vector_type(8))) unsigned short u16x8;
typedef __attribute__((ext_vector_type(4))) float f32x4;

// fp32 -> bf16 (RNE) and back, as raw bit ops
static __device__ __forceinline__ unsigned short f2bf(float f) {
    unsigned int u = __float_as_uint(f);
    unsigned int r = (u + 0x7fffu + ((u >> 16) & 1u)) >> 16;
    return (unsigned short)r;
}
static __device__ __forceinline__ float bf2f(unsigned short h) {
    return __uint_as_float(((unsigned int)h) << 16);
}

// ---------------------------------------------------------------------------
// init_k: zero the atomic regions (blocks [0, nZero)) + convW pre-swizzle
// (blocks nZero, nZero+1). Independent work fused to save a launch.
__global__ __launch_bounds__(256) void init_k(float4* __restrict__ zp, int n4,
                                              int nZeroBlocks,
                                              const float* __restrict__ W1,
                                              const float* __restrict__ W2,
                                              unsigned short* __restrict__ WB1,
                                              unsigned short* __restrict__ WB2) {
    int b = blockIdx.x;
    if (b < nZeroBlocks) {
        int i = b * blockDim.x + threadIdx.x;
        if (i < n4) zp[i] = make_float4(0.f, 0.f, 0.f, 0.f);
    } else {
        int half = b - nZeroBlocks;          // 0 or 1
        const float* W = half ? W2 : W1;
        unsigned short* WB = half ? WB2 : WB1;
        for (int idx = threadIdx.x; idx < 2 * 3 * 6 * 64 * 8; idx += 256) {
            int j = idx & 7;
            int lane = (idx >> 3) & 63;
            int frag = idx >> 9;            // 0..35
            int cg = frag % 6;
            int rest = frag / 6;            // t*3 + ks
            int ks = rest % 3;
            int t = rest / 3;
            int k = ks * 32 + (lane >> 4) * 8 + j;
            int n = cg * 16 + (lane & 15);
            float w = W[k * FH + n];
            unsigned short h = f2bf(w);
            WB[idx] = (t == 0) ? h : f2bf(w - bf2f(h));
        }
    }
}

// Kernel 1: in-degree count + per-edge rank (int atomics, exact)
__global__ void count_deg_k(const int* __restrict__ dst, int* __restrict__ deg,
                            unsigned short* __restrict__ rank16, int E) {
    int e = blockIdx.x * blockDim.x + threadIdx.x;
    if (e < E) rank16[e] = (unsigned short)atomicAdd(&deg[dst[e]], 1);
}

// Stage A: per-chunk (1024 deg) sums
__global__ __launch_bounds__(256) void partial_k(const int* __restrict__ deg,
                                                 int* __restrict__ blockSums, int n) {
    int base = blockIdx.x * 1024;
    int t = threadIdx.x;
    int s = 0;
#pragma unroll
    for (int j = 0; j < 4; j++) {
        int i = base + t * 4 + j;
        if (i < n) s += deg[i];
    }
    __shared__ int red[4];
    for (int off = 32; off > 0; off >>= 1) s += __shfl_down(s, off, 64);
    if ((t & 63) == 0) red[t >> 6] = s;
    __syncthreads();
    if (t == 0) blockSums[blockIdx.x] = red[0] + red[1] + red[2] + red[3];
}

// emit_k: each block scans blockSums in LDS (nb <= 256) for its offset,
// then per-chunk exclusive scan + writes rowstart + fused dis.
__global__ __launch_bounds__(256) void emit_k(const int* __restrict__ deg,
                                              const int* __restrict__ blockSums,
                                              int* __restrict__ rowstart,
                                              float* __restrict__ dis,
                                              int n, int nb) {
    __shared__ int sh[256];
    int t = threadIdx.x;
    sh[t] = (t < nb) ? blockSums[t] : 0;
    __syncthreads();
    for (int off = 1; off < 256; off <<= 1) {
        int v = 0;
        if (t >= off) v = sh[t - off];
        __syncthreads();
        if (t >= off) sh[t] += v;
        __syncthreads();
    }
    int blockBase = (blockIdx.x == 0) ? 0 : sh[blockIdx.x - 1];
    __syncthreads();

    int base = blockIdx.x * 1024;
    int d[4];
    int s = 0;
#pragma unroll
    for (int j = 0; j < 4; j++) {
        int i = base + t * 4 + j;
        d[j] = (i < n) ? deg[i] : 0;
        s += d[j];
    }
    sh[t] = s;
    __syncthreads();
    for (int off = 1; off < 256; off <<= 1) {
        int v = 0;
        if (t >= off) v = sh[t - off];
        __syncthreads();
        if (t >= off) sh[t] += v;
        __syncthreads();
    }
    int run = blockBase + ((t == 0) ? 0 : sh[t - 1]);
#pragma unroll
    for (int j = 0; j < 4; j++) {
        int i = base + t * 4 + j;
        if (i < n) {
            rowstart[i] = run;
            dis[i] = rsqrtf((float)d[j] + 1.0f);
        }
        run += d[j];
    }
    if (blockIdx.x == gridDim.x - 1 && t == 255) rowstart[n] = run;
}

// Kernel 4: fill CSR — atomic-free (rank precomputed), uint16 entries
__global__ void fill_k(const int* __restrict__ src, const int* __restrict__ dst,
                       const int* __restrict__ rowstart,
                       const unsigned short* __restrict__ rank16,
                       unsigned short* __restrict__ csr, int E) {
    int e = blockIdx.x * blockDim.x + threadIdx.x;
    if (e < E) {
        int pos = rowstart[dst[e]] + (int)rank16[e];
        csr[pos] = (unsigned short)src[e];
    }
}

// ---------------------------------------------------------------------------
// MFMA GEMM: Yb[r][c] = bf16( (sum_k X[r][k]*W[k][c]) * scale[r] ).
// INMODE 0: A from fp32 Xf, split hi/lo in-register, 3 terms (AhBh+AhBl+AlBh).
// INMODE 1: A from bf16 Xb, 2 terms (AhBh+AhBl).
// Block: 64 rows x 96 cols, 4 waves as 2 wave-rows x 2 wave-cols. No LDS.
template <int INMODE>
__global__ __launch_bounds__(256, 3) void gemm_mfma_k(
    const float* __restrict__ Xf, const unsigned short* __restrict__ Xb,
    const unsigned short* __restrict__ WB, const float* __restrict__ scale,
    unsigned short* __restrict__ Yb, int nrows) {
    int lane = threadIdx.x & 63;
    int wid  = threadIdx.x >> 6;
    int wr = wid >> 1, wc = wid & 1;
    int row0 = blockIdx.x * 64 + wr * 32;

    // B fragments in registers for the whole kernel (18 x b128)
    bf16x8 b[2][3][3];
#pragma unroll
    for (int t = 0; t < 2; t++)
#pragma unroll
        for (int ks = 0; ks < 3; ks++)
#pragma unroll
            for (int cg = 0; cg < 3; cg++) {
                int frag = (t * 3 + ks) * 6 + wc * 3 + cg;
                b[t][ks][cg] = *(const bf16x8*)(WB + frag * 512 + lane * 8);
            }

    f32x4 acc[2][3];
#pragma unroll
    for (int rg = 0; rg < 2; rg++)
#pragma unroll
        for (int cg = 0; cg < 3; cg++) acc[rg][cg] = (f32x4){0.f, 0.f, 0.f, 0.f};

    int r0 = lane & 15;
    int kcol = (lane >> 4) * 8;
#pragma unroll
    for (int ks = 0; ks < 3; ks++) {
        bf16x8 ah[2], al[2];
#pragma unroll
        for (int rg = 0; rg < 2; rg++) {
            if (INMODE == 1) {
                size_t off = (size_t)(row0 + rg * 16 + r0) * FH + ks * 32 + kcol;
                ah[rg] = *(const bf16x8*)(Xb + off);
            } else {
                int rr = row0 + rg * 16 + r0;
                if (rr >= nrows) rr = nrows - 1;
                const float* xp = Xf + (size_t)rr * FH + ks * 32 + kcol;
                float4 v0 = *(const float4*)xp;
                float4 v1 = *(const float4*)(xp + 4);
                float xv[8] = {v0.x, v0.y, v0.z, v0.w, v1.x, v1.y, v1.z, v1.w};
                bf16x8 hh, ll;
#pragma unroll
                for (int j = 0; j < 8; j++) {
                    unsigned short h = f2bf(xv[j]);
                    hh[j] = (short)h;
                    ll[j] = (short)f2bf(xv[j] - bf2f(h));
                }
                ah[rg] = hh;
                al[rg] = ll;
            }
        }
#pragma unroll
        for (int rg = 0; rg < 2; rg++)
#pragma unroll
            for (int cg = 0; cg < 3; cg++)
                acc[rg][cg] = __builtin_amdgcn_mfma_f32_16x16x32_bf16(
                    ah[rg], b[0][ks][cg], acc[rg][cg], 0, 0, 0);
#pragma unroll
        for (int rg = 0; rg < 2; rg++)
#pragma unroll
            for (int cg = 0; cg < 3; cg++)
                acc[rg][cg] = __builtin_amdgcn_mfma_f32_16x16x32_bf16(
                    ah[rg], b[1][ks][cg], acc[rg][cg], 0, 0, 0);
        if (INMODE == 0) {
#pragma unroll
            for (int rg = 0; rg < 2; rg++)
#pragma unroll
                for (int cg = 0; cg < 3; cg++)
                    acc[rg][cg] = __builtin_amdgcn_mfma_f32_16x16x32_bf16(
                        al[rg], b[0][ks][cg], acc[rg][cg], 0, 0, 0);
        }
    }

    // Epilogue: C/D layout col=lane&15, row=(lane>>4)*4+reg (m89-verified)
#pragma unroll
    for (int rg = 0; rg < 2; rg++) {
#pragma unroll
        for (int r = 0; r < 4; r++) {
            int row = row0 + rg * 16 + (lane >> 4) * 4 + r;
            if (row < nrows) {
                float s = scale[row];
#pragma unroll
                for (int cg = 0; cg < 3; cg++) {
                    int col = wc * 48 + cg * 16 + (lane & 15);
                    Yb[(size_t)row * FH + col] = f2bf(acc[rg][cg][r] * s);
                }
            }
        }
    }
}

// ---------------------------------------------------------------------------
// Gather: 12 threads/node, ushort8 (16B) loads, strip-8 (8 outstanding loads),
// fp32 accumulate, bf16 output. Used for both layers.
__global__ __launch_bounds__(256) void gather12_k(
    const unsigned short* __restrict__ hXb, const float* __restrict__ dis,
    const int* __restrict__ rowstart, const unsigned short* __restrict__ csr,
    const float* __restrict__ bias, unsigned short* __restrict__ outB, int n) {
    int idx = blockIdx.x * blockDim.x + threadIdx.x;
    if (idx >= n * 12) return;
    int node = idx / 12;
    int f8 = (idx - node * 12) * 8;
    int s = rowstart[node];
    int e = rowstart[node + 1];
    u16x8 sv = *(const u16x8*)&hXb[node * FH + f8];
    float a[8];
#pragma unroll
    for (int j = 0; j < 8; j++) a[j] = bf2f((unsigned short)sv[j]);
    int p = s;
    for (; p + 8 <= e; p += 8) {
        int i0 = csr[p],     i1 = csr[p + 1], i2 = csr[p + 2], i3 = csr[p + 3];
        int i4 = csr[p + 4], i5 = csr[p + 5], i6 = csr[p + 6], i7 = csr[p + 7];
        u16x8 v0 = *(const u16x8*)&hXb[i0 * FH + f8];
        u16x8 v1 = *(const u16x8*)&hXb[i1 * FH + f8];
        u16x8 v2 = *(const u16x8*)&hXb[i2 * FH + f8];
        u16x8 v3 = *(const u16x8*)&hXb[i3 * FH + f8];
        u16x8 v4 = *(const u16x8*)&hXb[i4 * FH + f8];
        u16x8 v5 = *(const u16x8*)&hXb[i5 * FH + f8];
        u16x8 v6 = *(const u16x8*)&hXb[i6 * FH + f8];
        u16x8 v7 = *(const u16x8*)&hXb[i7 * FH + f8];
#pragma unroll
        for (int j = 0; j < 8; j++) {
            a[j] += ((bf2f((unsigned short)v0[j]) + bf2f((unsigned short)v1[j]))
                   + (bf2f((unsigned short)v2[j]) + bf2f((unsigned short)v3[j])))
                  + ((bf2f((unsigned short)v4[j]) + bf2f((unsigned short)v5[j]))
                   + (bf2f((unsigned short)v6[j]) + bf2f((unsigned short)v7[j])));
        }
    }
    for (; p + 4 <= e; p += 4) {
        int i0 = csr[p], i1 = csr[p + 1], i2 = csr[p + 2], i3 = csr[p + 3];
        u16x8 v0 = *(const u16x8*)&hXb[i0 * FH + f8];
        u16x8 v1 = *(const u16x8*)&hXb[i1 * FH + f8];
        u16x8 v2 = *(const u16x8*)&hXb[i2 * FH + f8];
        u16x8 v3 = *(const u16x8*)&hXb[i3 * FH + f8];
#pragma unroll
        for (int j = 0; j < 8; j++) {
            a[j] += (bf2f((unsigned short)v0[j]) + bf2f((unsigned short)v1[j]))
                  + (bf2f((unsigned short)v2[j]) + bf2f((unsigned short)v3[j]));
        }
    }
    for (; p < e; p++) {
        int i0 = csr[p];
        u16x8 v0 = *(const u16x8*)&hXb[i0 * FH + f8];
#pragma unroll
        for (int j = 0; j < 8; j++) a[j] += bf2f((unsigned short)v0[j]);
    }
    float dn = dis[node];
    float4 bv0 = *(const float4*)&bias[f8];
    float4 bv1 = *(const float4*)&bias[f8 + 4];
    float bb[8] = {bv0.x, bv0.y, bv0.z, bv0.w, bv1.x, bv1.y, bv1.z, bv1.w};
    u16x8 hh;
#pragma unroll
    for (int j = 0; j < 8; j++) hh[j] = f2bf(fmaxf(a[j] * dn + bb[j], 0.0f));
    *(u16x8*)&outB[node * FH + f8] = hh;
}

// Kernel 7: pooling — batch is SORTED; register accumulation with boundary
// flush. CH=32 nodes/block -> ~1564 blocks for latency hiding.
__global__ __launch_bounds__(128) void pool3_k(const unsigned short* __restrict__ h,
                                               const int* __restrict__ bat,
                                               float* __restrict__ pooled,
                                               float* __restrict__ cnt, int n) {
    const int CH = 32;
    int beg = blockIdx.x * CH;
    if (beg >= n) return;
    int end = min(beg + CH, n);
    int t = threadIdx.x;
    if (t < FH) {
        float acc = 0.f;
        int g = bat[beg];
        for (int node = beg; node < end; ++node) {
            int gg = bat[node];
            if (gg != g) { atomicAdd(&pooled[g * FH + t], acc); acc = 0.f; g = gg; }
            acc += bf2f(h[(size_t)node * FH + t]);
        }
        atomicAdd(&pooled[g * FH + t], acc);
    } else if (t == FH) {
        float c = 0.f;
        int g = bat[beg];
        for (int node = beg; node < end; ++node) {
            int gg = bat[node];
            if (gg != g) { atomicAdd(&cnt[g], c); c = 0.f; g = gg; }
            c += 1.f;
        }
        atomicAdd(&cnt[g], c);
    }
}

// Kernel 8: heads — one block per graph
__global__ __launch_bounds__(128) void head_k(const float* __restrict__ pooled,
                                              const float* __restrict__ cnt,
                                              const float* __restrict__ u,
                                              const float* __restrict__ aW1, const float* __restrict__ ab1,
                                              const float* __restrict__ aW2, const float* __restrict__ ab2,
                                              const float* __restrict__ cW1, const float* __restrict__ cb1,
                                              const float* __restrict__ cW2, const float* __restrict__ cb2,
                                              float* __restrict__ out, int G) {
    int g = blockIdx.x;
    int t = threadIdx.x;
    __shared__ float comb[FH + GU];
    __shared__ float hidA[FH];
    __shared__ float hidC[FH];
    __shared__ float tmp[FH];
    float c = fmaxf(cnt[g], 1.0f);
    if (t < FH) comb[t] = pooled[g * FH + t] / c;
    else if (t < FH + GU) comb[t] = u[g * GU + (t - FH)];
    __syncthreads();
    if (t < FH) {
        float a = ab1[t], cc = cb1[t];
        for (int k = 0; k < FH + GU; k++) {
            float cv = comb[k];
            a += cv * aW1[k * FH + t];
            cc += cv * cW1[k * FH + t];
        }
        hidA[t] = fmaxf(a, 0.0f);
        hidC[t] = fmaxf(cc, 0.0f);
    }
    __syncthreads();
    if (t < GA) {
        float a = ab2[t];
        for (int j = 0; j < FH; j++) a += hidA[j] * aW2[j * GA + t];
        out[g * GA + t] = a;
    }
    if (t >= 32 && t < 32 + FH) tmp[t - 32] = hidC[t - 32] * cW2[t - 32];
    __syncthreads();
    if (t == 0) {
        float v = cb2[0];
        for (int j = 0; j < FH; j++) v += tmp[j];
        out[G * GA + g] = v;
    }
}

extern "C" void kernel_launch(void* const* d_in, const int* in_sizes, int n_in,
                              void* d_out, int out_size, void* d_ws, size_t ws_size,
                              hipStream_t stream) {
    const float* x   = (const float*)d_in[0];
    const int*   ei  = (const int*)d_in[1];
    const int*   bat = (const int*)d_in[2];
    const float* u   = (const float*)d_in[3];
    const float* W1  = (const float*)d_in[4];
    const float* b1  = (const float*)d_in[5];
    const float* W2  = (const float*)d_in[6];
    const float* b2  = (const float*)d_in[7];
    const float* aW1 = (const float*)d_in[8];
    const float* ab1 = (const float*)d_in[9];
    const float* aW2 = (const float*)d_in[10];
    const float* ab2 = (const float*)d_in[11];
    const float* cW1 = (const float*)d_in[12];
    const float* cb1 = (const float*)d_in[13];
    const float* cW2 = (const float*)d_in[14];
    const float* cb2 = (const float*)d_in[15];
    float* out = (float*)d_out;

    const int N = in_sizes[0] / FH;
    const int E = in_sizes[1] / 2;
    const int G = in_sizes[3] / GU;
    const int NPAD = (N + 63) / 64 * 64;   // 50048

    const int* src = ei;
    const int* dst = ei + E;

    // Workspace layout (float units, 64-aligned blocks)
    float* ws = (float*)d_ws;
    size_t o = 0;
    int*   degI     = (int*)(ws + o);   o += NPAD;
    float* pooled   = ws + o;           o += NG * FH;
    float* cnt      = ws + o;           o += 64;
    size_t zero_elems = o;                                     // zero [0, o)
    float* dis      = ws + o;           o += NPAD;
    int*   rowstart = (int*)(ws + o);   o += NPAD;             // N+1
    int*   blockSums= (int*)(ws + o);   o += 512;
    unsigned short* rank16 = (unsigned short*)(ws + o); o += ((size_t)(E + 1) / 2 + 63) / 64 * 64;
    unsigned short* csr16  = (unsigned short*)(ws + o); o += ((size_t)(E + 1) / 2 + 63) / 64 * 64;
    unsigned short* WB1 = (unsigned short*)(ws + o); o += 9216;  // 18432 ushorts
    unsigned short* WB2 = (unsigned short*)(ws + o); o += 9216;
    unsigned short* XhB = (unsigned short*)(ws + o); o += (size_t)NPAD * FH / 2;  // layer1 out / layer2 out
    unsigned short* hXb = (unsigned short*)(ws + o); o += (size_t)NPAD * FH / 2;  // GEMM out
    (void)ws_size;

    unsigned short* h2b = XhB;   // layer-2 gather output (XhB dead after gemm2)

    int gridE = (E + 255) / 256;
    int gridG12 = (N * 12 + 255) / 256;
    int gridMfma = NPAD / 64;
    int nbScan = (N + 1023) / 1024;
    int gridPool = (N + 31) / 32;
    int n4zero = (int)(zero_elems / 4);
    int gridZero = (n4zero + 255) / 256;

    // init: zero atomic regions + convW (fused, independent work)
    init_k<<<gridZero + 2, 256, 0, stream>>>((float4*)ws, n4zero, gridZero,
                                             W1, W2, WB1, WB2);

    count_deg_k<<<gridE, 256, 0, stream>>>(dst, degI, rank16, E);
    partial_k<<<nbScan, 256, 0, stream>>>(degI, blockSums, N);
    emit_k<<<nbScan, 256, 0, stream>>>(degI, blockSums, rowstart, dis, N, nbScan);
    fill_k<<<gridE, 256, 0, stream>>>(src, dst, rowstart, rank16, csr16, E);

    // Layer 1 (GEMM reads fp32 x directly, converts+splits in-register)
    gemm_mfma_k<0><<<gridMfma, 256, 0, stream>>>(x, (const unsigned short*)nullptr,
                                                 WB1, dis, hXb, N);
    gather12_k<<<gridG12, 256, 0, stream>>>(hXb, dis, rowstart, csr16, b1, XhB, N);
    // Layer 2 (A = bf16, 2-term)
    gemm_mfma_k<1><<<gridMfma, 256, 0, stream>>>((const float*)nullptr, XhB,
                                                 WB2, dis, hXb, N);
    gather12_k<<<gridG12, 256, 0, stream>>>(hXb, dis, rowstart, csr16, b2, h2b, N);

    // Pool (sorted-batch register accumulation, CH=32) + heads
    pool3_k<<<gridPool, 128, 0, stream>>>(h2b, bat, pooled, cnt, N);
    head_k<<<G, 128, 0, stream>>>(pooled, cnt, u, aW1, ab1, aW2, ab2,
                                  cW1, cb1, cW2, cb2, out, G);
}